// Round 1
// baseline (384.393 us; speedup 1.0000x reference)
//
#include <hip/hip_runtime.h>
#include <stdint.h>

// Exact fp32 reproduction of the numpy reference requires no FMA contraction
// and identical association order everywhere below.
#pragma clang fp contract(off)

#define B_   4
#define NV_  6890
#define NF_  27552     // 2*13776
#define IMG_ 128
#define UV_  256
#define NPIX (IMG_*IMG_)

// ---------------------------------------------------------------- projection
__global__ void __launch_bounds__(256) project_k(
    const float* __restrict__ cam, const float* __restrict__ verts,
    float* __restrict__ vp) {
  int idx = blockIdx.x * 256 + threadIdx.x;
  if (idx >= B_ * NV_) return;
  int b = idx / NV_;
  float c0 = cam[b * 3 + 0], c1 = cam[b * 3 + 1], c2 = cam[b * 3 + 2];
  float tz = 500.0f / (64.0f * c0);                  // FLENGTH/(p*cam0), p=64
  const float* src = verts + (size_t)idx * 3;
  float* dst = vp + (size_t)idx * 3;
  dst[0] = c0 * (src[0] + c1);
  dst[1] = c0 * (src[1] + c2);
  dst[2] = src[2] + tz;
}

// ---------------------------------------------------------------- rasterizer
// One wave64 per (batch, face). Lanes stride over the face's pixel bbox
// (+2px safety margin so fp32-rounded "inside" never escapes our bbox).
// Depth test = atomicMin on (float_bits(zp)<<32 | face_id): reproduces the
// reference's min-depth with ties broken by lowest face index exactly.
__global__ void __launch_bounds__(256) raster_k(
    const float* __restrict__ vp, const int* __restrict__ faces,
    unsigned long long* __restrict__ zkey) {
  int gid = blockIdx.x * 256 + threadIdx.x;
  int wave = gid >> 6;
  int lane = gid & 63;
  if (wave >= B_ * NF_) return;
  int b = wave / NF_;
  int f = wave - b * NF_;

  int ia = faces[f * 3 + 0], ib = faces[f * 3 + 1], ic = faces[f * 3 + 2];
  const float* vb = vp + (size_t)b * NV_ * 3;
  float x0 = vb[ia * 3 + 0], y0 = vb[ia * 3 + 1], z0 = vb[ia * 3 + 2];
  float x1 = vb[ib * 3 + 0], y1 = vb[ib * 3 + 1], z1 = vb[ib * 3 + 2];
  float x2 = vb[ic * 3 + 0], y2 = vb[ic * 3 + 1], z2 = vb[ic * 3 + 2];

  float xmn = fminf(x0, fminf(x1, x2)), xmx = fmaxf(x0, fmaxf(x1, x2));
  float ymn = fminf(y0, fminf(y1, y2)), ymx = fmaxf(y0, fmaxf(y1, y2));
  // pixel centers: px[j]=(2j+1)/128-1, py[i]=1-(2i+1)/128
  int jlo = (int)floorf((xmn + 1.0f) * 64.0f - 0.5f) - 2;
  int jhi = (int)ceilf ((xmx + 1.0f) * 64.0f - 0.5f) + 2;
  int ilo = (int)floorf((1.0f - ymx) * 64.0f - 0.5f) - 2;
  int ihi = (int)ceilf ((1.0f - ymn) * 64.0f - 0.5f) + 2;
  if (jhi < 0 || ihi < 0 || jlo > IMG_ - 1 || ilo > IMG_ - 1) return;
  jlo = max(jlo, 0); ilo = max(ilo, 0);
  jhi = min(jhi, IMG_ - 1); ihi = min(ihi, IMG_ - 1);
  int bw = jhi - jlo + 1;
  int n = bw * (ihi - ilo + 1);

  // hoisted (pixel-independent) differences: bitwise identical to per-pixel
  float d21x = x2 - x1, d21y = y2 - y1;
  float d02x = x0 - x2, d02y = y0 - y2;
  float d10x = x1 - x0, d10y = y1 - y0;

  unsigned long long* zb = zkey + (size_t)b * NPIX;
  unsigned long long fkey = (unsigned long long)(unsigned int)f;

  for (int p = lane; p < n; p += 64) {
    int jj = jlo + (p % bw);
    int ii = ilo + (p / bw);
    float px = (float)(2 * jj + 1) / 128.0f - 1.0f;
    float py = 1.0f - (float)(2 * ii + 1) / 128.0f;
    float w0 = d21x * (py - y1) - d21y * (px - x1);
    float w1 = d02x * (py - y2) - d02y * (px - x2);
    float w2 = d10x * (py - y0) - d10y * (px - x0);
    float area = (w0 + w1) + w2;
    if (!(area > 0.0f)) continue;
    // conservative cheap filter; exact b>=0 test (matches numpy, incl. -0
    // underflow semantics) done after the division
    if (w0 < -1e-30f || w1 < -1e-30f || w2 < -1e-30f) continue;
    float b0 = w0 / area, b1 = w1 / area, b2 = w2 / area;
    if (!(b0 >= 0.0f && b1 >= 0.0f && b2 >= 0.0f)) continue;
    float invz = (b0 / z0 + b1 / z1) + b2 / z2;
    float zp = 1.0f / (invz == 0.0f ? 1.0f : invz);
    if (!(zp > 0.1f && zp < 25.0f)) continue;
    unsigned long long key =
        ((unsigned long long)__float_as_uint(zp) << 32) | fkey;
    atomicMin(zb + ii * IMG_ + jj, key);
  }
}

// ------------------------------------------------------------------- shading
#define TAP(ty, tx, wexpr)                                                   \
  {                                                                          \
    int ty_ = (ty), tx_ = (tx);                                              \
    float w_ = (wexpr);                                                      \
    float valid_ =                                                           \
        (tx_ >= 0 && tx_ < UV_ && ty_ >= 0 && ty_ < UV_) ? 1.0f : 0.0f;      \
    float wv_ = w_ * valid_;                                                 \
    int cy_ = min(max(ty_, 0), UV_ - 1), cx_ = min(max(tx_, 0), UV_ - 1);    \
    int o_ = cy_ * UV_ + cx_;                                                \
    cr = cr + img[o_] * wv_;                                                 \
    cg = cg + img[UV_ * UV_ + o_] * wv_;                                     \
    cb = cb + img[2 * UV_ * UV_ + o_] * wv_;                                 \
  }

__global__ void __launch_bounds__(256) shade_k(
    const float* __restrict__ vp, const int* __restrict__ faces,
    const float* __restrict__ uv, const float* __restrict__ samp,
    const unsigned long long* __restrict__ zkey, float* __restrict__ out) {
  int idx = blockIdx.x * 256 + threadIdx.x;
  if (idx >= B_ * NPIX) return;
  int b = idx / NPIX;
  int p = idx - b * NPIX;
  int ii = p / IMG_;
  int jj = p - ii * IMG_;

  unsigned long long key = zkey[idx];
  float cr = 0.0f, cg = 0.0f, cb = 0.0f;
  if (key != 0xFFFFFFFFFFFFFFFFull) {
    int f = (int)(key & 0xFFFFFFFFull);
    int ia = faces[f * 3 + 0], ib = faces[f * 3 + 1], ic = faces[f * 3 + 2];
    const float* vb = vp + (size_t)b * NV_ * 3;
    float x0 = vb[ia * 3 + 0], y0 = vb[ia * 3 + 1];
    float x1 = vb[ib * 3 + 0], y1 = vb[ib * 3 + 1];
    float x2 = vb[ic * 3 + 0], y2 = vb[ic * 3 + 1];
    float px = (float)(2 * jj + 1) / 128.0f - 1.0f;
    float py = 1.0f - (float)(2 * ii + 1) / 128.0f;
    float w0 = (x2 - x1) * (py - y1) - (y2 - y1) * (px - x1);
    float w1 = (x0 - x2) * (py - y2) - (y0 - y2) * (px - x2);
    float w2 = (x1 - x0) * (py - y0) - (y1 - y0) * (px - x0);
    float area = (w0 + w1) + w2;
    float s = (area == 0.0f) ? 1.0f : area;
    float b0 = w0 / s, b1 = w1 / s;
    int t0 = min(max((int)floorf(b0 * 3.0f), 0), 2);
    int t1 = min(max((int)floorf(b1 * 3.0f), 0), 2);

    // lazy texture fetch: textures[b,f,t0,t1,*,c] == bilinear(uv_imgs[b],
    // sampler[f, t0*3+t1]); lighting multiplier is exactly 1.0 -> skipped.
    const float* g = samp + ((size_t)f * 9 + (size_t)(t0 * 3 + t1)) * 2;
    float gx = g[0], gy = g[1];
    float x = (gx + 1.0f) * 128.0f - 0.5f;   // (g+1)*(W*0.5)-0.5, W=256
    float y = (gy + 1.0f) * 128.0f - 0.5f;
    float x0f = floorf(x), y0f = floorf(y);
    float wx = x - x0f, wy = y - y0f;
    int xi = (int)x0f, yi = (int)y0f;
    float omwx = 1.0f - wx, omwy = 1.0f - wy;
    const float* img = uv + (size_t)b * 3 * UV_ * UV_;
    // reference accumulation order: (y0,x0) + (y0,x0+1) + (y0+1,x0) + (y0+1,x0+1)
    TAP(yi,     xi,     omwx * omwy)
    TAP(yi,     xi + 1, wx * omwy)
    TAP(yi + 1, xi,     omwx * wy)
    TAP(yi + 1, xi + 1, wx * wy)
  }
  out[((size_t)b * 3 + 0) * NPIX + p] = cr;
  out[((size_t)b * 3 + 1) * NPIX + p] = cg;
  out[((size_t)b * 3 + 2) * NPIX + p] = cb;
}

// ------------------------------------------------------------------- launch
extern "C" void kernel_launch(void* const* d_in, const int* in_sizes, int n_in,
                              void* d_out, int out_size, void* d_ws,
                              size_t ws_size, hipStream_t stream) {
  const float* cam   = (const float*)d_in[0];
  const float* verts = (const float*)d_in[1];
  const float* uv    = (const float*)d_in[2];
  const float* samp  = (const float*)d_in[3];
  const int*   faces = (const int*)d_in[4];

  unsigned long long* zkey = (unsigned long long*)d_ws;           // 2 MiB
  float* vp = (float*)((char*)d_ws + (size_t)B_ * NPIX * 8);      // 330 KB

  hipMemsetAsync(zkey, 0xFF, (size_t)B_ * NPIX * 8, stream);
  project_k<<<(B_ * NV_ + 255) / 256, 256, 0, stream>>>(cam, verts, vp);
  int waves = B_ * NF_;
  raster_k<<<(waves * 64 + 255) / 256, 256, 0, stream>>>(vp, faces, zkey);
  shade_k<<<(B_ * NPIX + 255) / 256, 256, 0, stream>>>(vp, faces, uv, samp,
                                                       zkey, (float*)d_out);
}

// Round 2
// 370.135 us; speedup vs baseline: 1.0385x; 1.0385x over previous
//
#include <hip/hip_runtime.h>
#include <stdint.h>

// Exact fp32 reproduction of the numpy reference requires no FMA contraction
// and identical association order everywhere below.
#pragma clang fp contract(off)

#define B_   4
#define NV_  6890
#define NF_  27552     // 2*13776
#define IMG_ 128
#define UV_  256
#define NPIX (IMG_*IMG_)

// ---------------------------------------------------------------- projection
__global__ void __launch_bounds__(256) project_k(
    const float* __restrict__ cam, const float* __restrict__ verts,
    float* __restrict__ vp) {
  int idx = blockIdx.x * 256 + threadIdx.x;
  if (idx >= B_ * NV_) return;
  int b = idx / NV_;
  float c0 = cam[b * 3 + 0], c1 = cam[b * 3 + 1], c2 = cam[b * 3 + 2];
  float tz = 500.0f / (64.0f * c0);                  // FLENGTH/(p*cam0), p=64
  const float* src = verts + (size_t)idx * 3;
  float* dst = vp + (size_t)idx * 3;
  dst[0] = c0 * (src[0] + c1);
  dst[1] = c0 * (src[1] + c2);
  dst[2] = src[2] + tz;
}

// ---------------------------------------------------------------- rasterizer
// One wave64 per (batch, face). Lanes stride over the face's pixel bbox
// (+2px safety margin, proven bit-exact in round 1).
// Depth test = atomicMin on (float_bits(zp)<<32 | face_id): reproduces the
// reference's min-depth with ties broken by lowest face index exactly.
//
// R1 optimizations (both bit-safe):
//  * whole-face back-face reject: per-pixel area differs from the analytic
//    cross product by <= ~5e-5 (few ulp of <=32-magnitude intermediates), so
//    area_c < -1e-3 implies every per-pixel `area > 0` fails. |area_c|<=1e-3
//    falls through to the exact per-pixel path.
//  * (ii,jj) incremental update (q=64/bw, r=64%bw) replaces per-pixel
//    integer div/mod by runtime bw.
//  * px = fma(jj, 1/64, -127/128): (2j+1)/128-1 is a multiple of 2^-7 in
//    [-1,1] -> exactly representable -> identical bits to the reference.
__global__ void __launch_bounds__(256) raster_k(
    const float* __restrict__ vp, const int* __restrict__ faces,
    unsigned long long* __restrict__ zkey) {
  int gid = blockIdx.x * 256 + threadIdx.x;
  int wave = gid >> 6;
  int lane = gid & 63;
  if (wave >= B_ * NF_) return;
  int b = wave / NF_;
  int f = wave - b * NF_;

  int ia = faces[f * 3 + 0], ib = faces[f * 3 + 1], ic = faces[f * 3 + 2];
  const float* vb = vp + (size_t)b * NV_ * 3;
  float x0 = vb[ia * 3 + 0], y0 = vb[ia * 3 + 1], z0 = vb[ia * 3 + 2];
  float x1 = vb[ib * 3 + 0], y1 = vb[ib * 3 + 1], z1 = vb[ib * 3 + 2];
  float x2 = vb[ic * 3 + 0], y2 = vb[ic * 3 + 1], z2 = vb[ic * 3 + 2];

  // hoisted (pixel-independent) differences: bitwise identical to per-pixel
  float d21x = x2 - x1, d21y = y2 - y1;
  float d02x = x0 - x2, d02y = y0 - y2;
  float d10x = x1 - x0, d10y = y1 - y0;

  // conservative whole-face back-face reject (see header comment)
  float area_c = d10x * (-d02y) - d10y * (-d02x);   // cross(v1-v0, v2-v0)
  if (area_c < -1e-3f) return;

  float xmn = fminf(x0, fminf(x1, x2)), xmx = fmaxf(x0, fmaxf(x1, x2));
  float ymn = fminf(y0, fminf(y1, y2)), ymx = fmaxf(y0, fmaxf(y1, y2));
  // pixel centers: px[j]=(2j+1)/128-1, py[i]=1-(2i+1)/128
  int jlo = (int)floorf((xmn + 1.0f) * 64.0f - 0.5f) - 2;
  int jhi = (int)ceilf ((xmx + 1.0f) * 64.0f - 0.5f) + 2;
  int ilo = (int)floorf((1.0f - ymx) * 64.0f - 0.5f) - 2;
  int ihi = (int)ceilf ((1.0f - ymn) * 64.0f - 0.5f) + 2;
  if (jhi < 0 || ihi < 0 || jlo > IMG_ - 1 || ilo > IMG_ - 1) return;
  jlo = max(jlo, 0); ilo = max(ilo, 0);
  jhi = min(jhi, IMG_ - 1); ihi = min(ihi, IMG_ - 1);
  int bw = jhi - jlo + 1;
  int bh = ihi - ilo + 1;

  // incremental (row, col) walk: one int div per lane at init, then adds
  int q = 64 / bw;                 // wave-uniform (scalar)
  int r = 64 - q * bw;
  int ir = lane / bw;              // row index relative to ilo
  int jj = lane - ir * bw;         // col index relative to jlo

  unsigned long long* zb = zkey + (size_t)b * NPIX;
  unsigned long long fkey = (unsigned long long)(unsigned int)f;

  while (ir < bh) {
    int jA = jlo + jj;
    int iA = ilo + ir;
    // exact: (2j+1)/128-1 and 1-(2i+1)/128 are multiples of 2^-7 in [-1,1]
    float px = fmaf((float)jA, 0.015625f, -0.9921875f);
    float py = fmaf((float)iA, -0.015625f, 0.9921875f);
    float w0 = d21x * (py - y1) - d21y * (px - x1);
    float w1 = d02x * (py - y2) - d02y * (px - x2);
    float w2 = d10x * (py - y0) - d10y * (px - x0);
    float area = (w0 + w1) + w2;
    // advance before the conditional work (keeps the fall-through cheap)
    jj += r; ir += q;
    if (jj >= bw) { jj -= bw; ir += 1; }
    if (!(area > 0.0f)) continue;
    // conservative cheap filter; exact b>=0 test (matches numpy, incl. -0
    // underflow semantics) done after the division
    if (w0 < -1e-30f || w1 < -1e-30f || w2 < -1e-30f) continue;
    float b0 = w0 / area, b1 = w1 / area, b2 = w2 / area;
    if (!(b0 >= 0.0f && b1 >= 0.0f && b2 >= 0.0f)) continue;
    float invz = (b0 / z0 + b1 / z1) + b2 / z2;
    float zp = 1.0f / (invz == 0.0f ? 1.0f : invz);
    if (!(zp > 0.1f && zp < 25.0f)) continue;
    unsigned long long key =
        ((unsigned long long)__float_as_uint(zp) << 32) | fkey;
    atomicMin(zb + iA * IMG_ + jA, key);
  }
}

// ------------------------------------------------------------------- shading
#define TAP(ty, tx, wexpr)                                                   \
  {                                                                          \
    int ty_ = (ty), tx_ = (tx);                                              \
    float w_ = (wexpr);                                                      \
    float valid_ =                                                           \
        (tx_ >= 0 && tx_ < UV_ && ty_ >= 0 && ty_ < UV_) ? 1.0f : 0.0f;      \
    float wv_ = w_ * valid_;                                                 \
    int cy_ = min(max(ty_, 0), UV_ - 1), cx_ = min(max(tx_, 0), UV_ - 1);    \
    int o_ = cy_ * UV_ + cx_;                                                \
    cr = cr + img[o_] * wv_;                                                 \
    cg = cg + img[UV_ * UV_ + o_] * wv_;                                     \
    cb = cb + img[2 * UV_ * UV_ + o_] * wv_;                                 \
  }

__global__ void __launch_bounds__(256) shade_k(
    const float* __restrict__ vp, const int* __restrict__ faces,
    const float* __restrict__ uv, const float* __restrict__ samp,
    const unsigned long long* __restrict__ zkey, float* __restrict__ out) {
  int idx = blockIdx.x * 256 + threadIdx.x;
  if (idx >= B_ * NPIX) return;
  int b = idx / NPIX;
  int p = idx - b * NPIX;
  int ii = p / IMG_;
  int jj = p - ii * IMG_;

  unsigned long long key = zkey[idx];
  float cr = 0.0f, cg = 0.0f, cb = 0.0f;
  if (key != 0xFFFFFFFFFFFFFFFFull) {
    int f = (int)(key & 0xFFFFFFFFull);
    int ia = faces[f * 3 + 0], ib = faces[f * 3 + 1], ic = faces[f * 3 + 2];
    const float* vb = vp + (size_t)b * NV_ * 3;
    float x0 = vb[ia * 3 + 0], y0 = vb[ia * 3 + 1];
    float x1 = vb[ib * 3 + 0], y1 = vb[ib * 3 + 1];
    float x2 = vb[ic * 3 + 0], y2 = vb[ic * 3 + 1];
    float px = (float)(2 * jj + 1) / 128.0f - 1.0f;
    float py = 1.0f - (float)(2 * ii + 1) / 128.0f;
    float w0 = (x2 - x1) * (py - y1) - (y2 - y1) * (px - x1);
    float w1 = (x0 - x2) * (py - y2) - (y0 - y2) * (px - x2);
    float w2 = (x1 - x0) * (py - y0) - (y1 - y0) * (px - x0);
    float area = (w0 + w1) + w2;
    float s = (area == 0.0f) ? 1.0f : area;
    float b0 = w0 / s, b1 = w1 / s;
    int t0 = min(max((int)floorf(b0 * 3.0f), 0), 2);
    int t1 = min(max((int)floorf(b1 * 3.0f), 0), 2);

    // lazy texture fetch: textures[b,f,t0,t1,*,c] == bilinear(uv_imgs[b],
    // sampler[f, t0*3+t1]); lighting multiplier is exactly 1.0 -> skipped.
    const float* g = samp + ((size_t)f * 9 + (size_t)(t0 * 3 + t1)) * 2;
    float gx = g[0], gy = g[1];
    float x = (gx + 1.0f) * 128.0f - 0.5f;   // (g+1)*(W*0.5)-0.5, W=256
    float y = (gy + 1.0f) * 128.0f - 0.5f;
    float x0f = floorf(x), y0f = floorf(y);
    float wx = x - x0f, wy = y - y0f;
    int xi = (int)x0f, yi = (int)y0f;
    float omwx = 1.0f - wx, omwy = 1.0f - wy;
    const float* img = uv + (size_t)b * 3 * UV_ * UV_;
    // reference accumulation order: (y0,x0) + (y0,x0+1) + (y0+1,x0) + (y0+1,x0+1)
    TAP(yi,     xi,     omwx * omwy)
    TAP(yi,     xi + 1, wx * omwy)
    TAP(yi + 1, xi,     omwx * wy)
    TAP(yi + 1, xi + 1, wx * wy)
  }
  out[((size_t)b * 3 + 0) * NPIX + p] = cr;
  out[((size_t)b * 3 + 1) * NPIX + p] = cg;
  out[((size_t)b * 3 + 2) * NPIX + p] = cb;
}

// ------------------------------------------------------------------- launch
extern "C" void kernel_launch(void* const* d_in, const int* in_sizes, int n_in,
                              void* d_out, int out_size, void* d_ws,
                              size_t ws_size, hipStream_t stream) {
  const float* cam   = (const float*)d_in[0];
  const float* verts = (const float*)d_in[1];
  const float* uv    = (const float*)d_in[2];
  const float* samp  = (const float*)d_in[3];
  const int*   faces = (const int*)d_in[4];

  unsigned long long* zkey = (unsigned long long*)d_ws;           // 2 MiB
  float* vp = (float*)((char*)d_ws + (size_t)B_ * NPIX * 8);      // 330 KB

  hipMemsetAsync(zkey, 0xFF, (size_t)B_ * NPIX * 8, stream);
  project_k<<<(B_ * NV_ + 255) / 256, 256, 0, stream>>>(cam, verts, vp);
  int waves = B_ * NF_;
  raster_k<<<(waves * 64 + 255) / 256, 256, 0, stream>>>(vp, faces, zkey);
  shade_k<<<(B_ * NPIX + 255) / 256, 256, 0, stream>>>(vp, faces, uv, samp,
                                                       zkey, (float*)d_out);
}